// Round 6
// baseline (348.781 us; speedup 1.0000x reference)
//
#include <hip/hip_runtime.h>
#include <hip/hip_bf16.h>
#include <hip/hip_fp16.h>
#include <stdint.h>

// ---------------------------------------------------------------------------
// CLIPAttentionPooling. R6: S and proj GEMMs unified on mfma_i32_32x32x32_i8
// (half the instruction count per op vs 16x16x64; +12% MFMA ceiling) with
// split-i8 3-MFMA (hh + hi*lo + lo*hi; lo*lo dropped). Proj epilogue fuses
// bias + int16-grid re-quantization. attn fp16 in-place in S rows; AV fp16
// with XCD-aware swizzle + split-K=2. Single fused quant kernel.
// ---------------------------------------------------------------------------

using short8  = __attribute__((ext_vector_type(8))) short;
using half8   = __attribute__((ext_vector_type(8))) _Float16;
using float4v = __attribute__((ext_vector_type(4))) float;
using int4v   = __attribute__((ext_vector_type(4))) int;
using int16v  = __attribute__((ext_vector_type(16))) int;

// q/k int16 grid: covers +-6.0, v = QS*(256*hi+lo)
#define QS        (6.0f / 32768.0f)
#define INV_S     (32768.0f / 6.0f)
#define INV_S256  (128.0f / 6.0f)
#define C_HH      (65536.0f * QS * QS)
#define C_X       (256.0f * QS * QS)

// x grid: +-6.0 ; W grid: +-0.25
#define SX        (6.0f / 32768.0f)
#define SW        (0.25f / 32768.0f)
#define P_HH      (65536.0f * SX * SW)
#define P_X       (256.0f * SX * SW)

#define GLOAD_LDS16(gptr, ldsptr)                                              \
  __builtin_amdgcn_global_load_lds(                                            \
      (__attribute__((address_space(1))) void*)(uintptr_t)(gptr),              \
      (__attribute__((address_space(3))) void*)(unsigned)(uintptr_t)(ldsptr),  \
      16, 0, 0)

// ---------------------------------------------------------------------------
// Unified split-i8 GEMM, 32x32x32 MFMA, 128x128 tile, BK=32.
// C = c_hh*(Ahi Bhi^T) + c_x*(Ahi Blo^T + Alo Bhi^T)   [lo*lo dropped]
// EPI=0: store fp32 to Ch.  EPI=1: add bias (biasQ cols<1024 else biasK),
//        re-quantize to int16 grid, store i8 hi/lo planes to Ch/Cl.
template <int EPI>
__global__ __launch_bounds__(256) void gemm_i8_32(
    const int8_t* __restrict__ Ahi, const int8_t* __restrict__ Alo,
    const int8_t* __restrict__ Bhi, const int8_t* __restrict__ Blo,
    const float* __restrict__ biasQ, const float* __restrict__ biasK,
    void* __restrict__ Ch, void* __restrict__ Cl,
    int lda, int ldb, int ldc, int K, float c_hh, float c_x)
{
  __shared__ __align__(16) int8_t sAh[128 * 32];
  __shared__ __align__(16) int8_t sAl[128 * 32];
  __shared__ __align__(16) int8_t sBh[128 * 32];
  __shared__ __align__(16) int8_t sBl[128 * 32];

  const int tid   = threadIdx.x;
  const int wave  = tid >> 6;
  const int lane  = tid & 63;
  const int m32   = lane & 31;   // row/col within 32x32 subtile
  const int khalf = lane >> 5;   // K-half selector (A/B frag)
  const int wm    = wave & 1;    // wave row-half of 128x128 tile
  const int wn    = wave >> 1;   // wave col-half
  const int row0  = blockIdx.y * 128;
  const int col0  = blockIdx.x * 128;

  // staging: 32 B per row; 2 lanes/row; each wave stages 32 rows per plane
  const int seg  = lane & 1;
  const int rsub = lane >> 1;

  int16v hh[2][2], cc[2][2];
#pragma unroll
  for (int i = 0; i < 2; ++i)
#pragma unroll
    for (int j = 0; j < 2; ++j) {
      hh[i][j] = (int16v)(0);
      cc[i][j] = (int16v)(0);
    }

  for (int k0 = 0; k0 < K; k0 += 32) {
    {
      const int trow = wave * 32;  // wave-uniform base row for this plane pass
      const size_t goffA = (size_t)(row0 + trow + rsub) * lda + k0 + seg * 16;
      const size_t goffB = (size_t)(col0 + trow + rsub) * ldb + k0 + seg * 16;
      GLOAD_LDS16(Ahi + goffA, &sAh[trow * 32]);
      GLOAD_LDS16(Alo + goffA, &sAl[trow * 32]);
      GLOAD_LDS16(Bhi + goffB, &sBh[trow * 32]);
      GLOAD_LDS16(Blo + goffB, &sBl[trow * 32]);
    }
    __syncthreads();

    // A-frag (K-doubling analogy, 16x16 variant verified R4):
    // lane holds A[m = lane&31][k = khalf*16 + 0..15]
    int4v ah[2], al[2], bh[2], bl[2];
#pragma unroll
    for (int i = 0; i < 2; ++i) {
      const int ar = (wm * 64 + i * 32 + m32) * 32 + khalf * 16;
      ah[i] = *(const int4v*)&sAh[ar];
      al[i] = *(const int4v*)&sAl[ar];
    }
#pragma unroll
    for (int j = 0; j < 2; ++j) {
      const int br = (wn * 64 + j * 32 + m32) * 32 + khalf * 16;
      bh[j] = *(const int4v*)&sBh[br];
      bl[j] = *(const int4v*)&sBl[br];
    }

#pragma unroll
    for (int i = 0; i < 2; ++i)
#pragma unroll
      for (int j = 0; j < 2; ++j) {
        hh[i][j] = __builtin_amdgcn_mfma_i32_32x32x32_i8(ah[i], bh[j], hh[i][j], 0, 0, 0);
        cc[i][j] = __builtin_amdgcn_mfma_i32_32x32x32_i8(ah[i], bl[j], cc[i][j], 0, 0, 0);
        cc[i][j] = __builtin_amdgcn_mfma_i32_32x32x32_i8(al[i], bh[j], cc[i][j], 0, 0, 0);
      }
    __syncthreads();
  }

  // 32x32 C/D layout [verified m74/m101, dtype-independent]:
  // col = lane&31, row = (reg&3) + 8*(reg>>2) + 4*(lane>>5)
#pragma unroll
  for (int i = 0; i < 2; ++i) {
#pragma unroll
    for (int j = 0; j < 2; ++j) {
      const int ccol = col0 + wn * 64 + j * 32 + m32;
      const float* bp = nullptr;
      if (EPI == 1) bp = (ccol < 1024) ? biasQ : (biasK - 1024);
#pragma unroll
      for (int r = 0; r < 16; ++r) {
        const int crow = row0 + wm * 64 + i * 32 + (r & 3) + 8 * (r >> 2) + 4 * khalf;
        float v = c_hh * (float)hh[i][j][r] + c_x * (float)cc[i][j][r];
        if (EPI == 0) {
          ((float*)Ch)[(size_t)crow * ldc + ccol] = v;
        } else {
          v += bp[ccol];
          int hi = (int)lrintf(v * INV_S256);
          hi = hi > 127 ? 127 : (hi < -127 ? -127 : hi);
          int lo = (int)lrintf(v * INV_S - 256.0f * (float)hi);
          lo = lo > 127 ? 127 : (lo < -127 ? -127 : lo);
          ((int8_t*)Ch)[(size_t)crow * ldc + ccol] = (int8_t)hi;
          ((int8_t*)Cl)[(size_t)crow * ldc + ccol] = (int8_t)lo;
        }
      }
    }
  }
}

// ---------------------------------------------------------------------------
// AV: out_part = attn * x. fp16 MFMA 16x16x32, split-K=2, XCD-aware swizzle:
// all 16 blocks (8 cols x 2 z) of one 128-row attn band share (id mod 8).
__global__ __launch_bounds__(256) void gemm_av(
    const uint16_t* __restrict__ A, const uint16_t* __restrict__ B,
    float* __restrict__ part)
{
  __shared__ uint16_t sA[128 * 32];
  __shared__ uint16_t sB[128 * 32];

  const int L    = blockIdx.x;                 // 0..511
  const int slot = L >> 3;                     // 0..63
  const int band = (L & 7) + 8 * (slot >> 4);  // 0..31
  const int rem  = slot & 15;
  const int xcol = rem & 7;
  const int z    = rem >> 3;

  const int tid  = threadIdx.x;
  const int wave = tid >> 6;
  const int lane = tid & 63;
  const int quad = lane >> 4;
  const int t16  = lane & 15;
  const int wm   = wave & 1;
  const int wn   = wave >> 1;
  const int row0 = band * 128;
  const int col0 = xcol * 128;

  const int seg  = lane & 3;
  const int rsub = lane >> 2;

  float4v acc[4][4];
#pragma unroll
  for (int i = 0; i < 4; ++i)
#pragma unroll
    for (int j = 0; j < 4; ++j)
      acc[i][j] = (float4v){0.f, 0.f, 0.f, 0.f};

  const int k_begin = z * 2048, k_end = k_begin + 2048;
  for (int k0 = k_begin; k0 < k_end; k0 += 32) {
#pragma unroll
    for (int r = 0; r < 2; ++r) {
      const int trow = r * 64 + wave * 16;
      const size_t goffA = (size_t)(row0 + trow + rsub) * 8192 + k0 + seg * 8;
      const size_t goffB = (size_t)(col0 + trow + rsub) * 4096 + k0 + seg * 8;
      GLOAD_LDS16(A + goffA, &sA[trow * 32]);
      GLOAD_LDS16(B + goffB, &sB[trow * 32]);
    }
    __syncthreads();

    half8 af[4], bf[4];
#pragma unroll
    for (int i = 0; i < 4; ++i)
      af[i] = *(const half8*)&sA[(wm * 64 + i * 16 + t16) * 32 + quad * 8];
#pragma unroll
    for (int j = 0; j < 4; ++j)
      bf[j] = *(const half8*)&sB[(wn * 64 + j * 16 + t16) * 32 + quad * 8];

#pragma unroll
    for (int i = 0; i < 4; ++i)
#pragma unroll
      for (int j = 0; j < 4; ++j)
        acc[i][j] = __builtin_amdgcn_mfma_f32_16x16x32_f16(af[i], bf[j], acc[i][j], 0, 0, 0);
    __syncthreads();
  }

#pragma unroll
  for (int i = 0; i < 4; ++i) {
#pragma unroll
    for (int j = 0; j < 4; ++j) {
      const int ccol = col0 + wn * 64 + j * 16 + t16;
#pragma unroll
      for (int r = 0; r < 4; ++r) {
        const int crow = row0 + wm * 64 + i * 16 + quad * 4 + r;
        part[(size_t)z * 4096 * 1024 + (size_t)crow * 1024 + ccol] = acc[i][j][r];
      }
    }
  }
}

// ---------------------------------------------------------------------------
// One fused quantizer: x (1M float4s, +-6 grid) then Wq, Wk (262144 each,
// +-0.25 grid) into i8 hi/lo planes. Wk planes at offset D*D.
__global__ __launch_bounds__(256) void quant_all(
    const float* __restrict__ x, const float* __restrict__ Wq,
    const float* __restrict__ Wk,
    int8_t* __restrict__ xhi, int8_t* __restrict__ xlo,
    int8_t* __restrict__ whi, int8_t* __restrict__ wlo)
{
  int i = blockIdx.x * blockDim.x + threadIdx.x;  // 0..1572863
  const float* src; int8_t* dh; int8_t* dl; int idx; float s256, s;
  if (i < 1048576)      { src = x;  idx = i;           dh = xhi; dl = xlo;
                          s256 = INV_S256; s = INV_S; }
  else if (i < 1310720) { src = Wq; idx = i - 1048576; dh = whi; dl = wlo;
                          s256 = 512.0f; s = 131072.0f; }
  else                  { src = Wk; idx = i - 1310720; dh = whi + 1048576;
                          dl = wlo + 1048576; s256 = 512.0f; s = 131072.0f; }
  float4 v = ((const float4*)src)[idx];
  float vv[4] = {v.x, v.y, v.z, v.w};
  int hp = 0, lp = 0;
#pragma unroll
  for (int c = 0; c < 4; ++c) {
    int h = (int)lrintf(vv[c] * s256);
    h = h > 127 ? 127 : (h < -127 ? -127 : h);
    int l = (int)lrintf(vv[c] * s - 256.0f * (float)h);
    l = l > 127 ? 127 : (l < -127 ? -127 : l);
    hp |= (h & 0xff) << (8 * c);
    lp |= (l & 0xff) << (8 * c);
  }
  ((int*)dh)[idx] = hp;
  ((int*)dl)[idx] = lp;
}

// x [4096 x 1024] fp32 -> xT [1024 x 4096] fp16
__global__ __launch_bounds__(1024) void transpose_cast_f16(
    const float* __restrict__ x, uint16_t* __restrict__ xT)
{
  __shared__ float tile[32][33];
  const int tx = threadIdx.x, ty = threadIdx.y;
  const int col = blockIdx.x * 32 + tx;
  const int row = blockIdx.y * 32 + ty;
  tile[ty][tx] = x[(size_t)row * 1024 + col];
  __syncthreads();
  __half h = __float2half_rn(tile[tx][ty]);
  xT[(size_t)(blockIdx.x * 32 + ty) * 4096 + blockIdx.y * 32 + tx] = *(uint16_t*)&h;
}

// per-row softmax over S fp32 [4096 x 4096]; attn fp16 written in-place into
// the first half of each 16 KB S row.
__global__ __launch_bounds__(1024) void softmax_rows(float* __restrict__ S)
{
  const int row = blockIdx.x;
  const size_t base = (size_t)row * 4096;
  const int tid = threadIdx.x;
  const int wid = tid >> 6, lane = tid & 63;
  __shared__ float red[16];

  float4 v = ((const float4*)(S + base))[tid];
  float m = fmaxf(fmaxf(v.x, v.y), fmaxf(v.z, v.w));
#pragma unroll
  for (int off = 32; off; off >>= 1) m = fmaxf(m, __shfl_xor(m, off));
  if (lane == 0) red[wid] = m;
  __syncthreads();
  float mall = red[0];
#pragma unroll
  for (int i = 1; i < 16; ++i) mall = fmaxf(mall, red[i]);

  float4 e;
  e.x = __expf(v.x - mall);
  e.y = __expf(v.y - mall);
  e.z = __expf(v.z - mall);
  e.w = __expf(v.w - mall);
  float s = e.x + e.y + e.z + e.w;
#pragma unroll
  for (int off = 32; off; off >>= 1) s += __shfl_xor(s, off);
  __syncthreads();
  if (lane == 0) red[wid] = s;
  __syncthreads();
  float sall = 0.f;
#pragma unroll
  for (int i = 0; i < 16; ++i) sall += red[i];
  const float inv = 1.0f / sall;

  union { __half h[4]; short4 s4; } u;
  u.h[0] = __float2half_rn(e.x * inv);
  u.h[1] = __float2half_rn(e.y * inv);
  u.h[2] = __float2half_rn(e.z * inv);
  u.h[3] = __float2half_rn(e.w * inv);
  ((short4*)S)[(size_t)row * 2048 + tid] = u.s4;
}

// out = p0 + p1 (split-K reduce)
__global__ __launch_bounds__(256) void add2(
    const float* __restrict__ p0, const float* __restrict__ p1,
    float* __restrict__ out, int n4)
{
  int i = blockIdx.x * blockDim.x + threadIdx.x;
  if (i < n4) {
    float4 a = ((const float4*)p0)[i];
    float4 b = ((const float4*)p1)[i];
    float4 o = {a.x + b.x, a.y + b.y, a.z + b.z, a.w + b.w};
    ((float4*)out)[i] = o;
  }
}

extern "C" void kernel_launch(void* const* d_in, const int* in_sizes, int n_in,
                              void* d_out, int out_size, void* d_ws, size_t ws_size,
                              hipStream_t stream) {
  const int N = 4096, D = 1024;
  const float* x  = (const float*)d_in[0];
  const float* Wq = (const float*)d_in[1];
  const float* bq = (const float*)d_in[2];
  const float* Wk = (const float*)d_in[3];
  const float* bk = (const float*)d_in[4];
  float* out = (float*)d_out;

  // workspace layout (MiB offsets), total 108 MiB
  char* w = (char*)d_ws;
  const size_t MiB = 1024 * 1024;
  int8_t*   xq_hi  = (int8_t*)  (w + 0   * MiB);  // [N x D]      (dead after proj)
  int8_t*   xq_lo  = (int8_t*)  (w + 4   * MiB);
  int8_t*   Wqk_hi = (int8_t*)  (w + 8   * MiB);  // [2048 x D]   (dead after proj)
  int8_t*   Wqk_lo = (int8_t*)  (w + 10  * MiB);
  int8_t*   qk_hi  = (int8_t*)  (w + 12  * MiB);  // [N x 2048]   (dead after S)
  int8_t*   qk_lo  = (int8_t*)  (w + 20  * MiB);
  float*    S      = (float*)   (w + 36  * MiB);  // [N x N] fp32, 64 MiB
  uint16_t* xTh    = (uint16_t*)(w + 100 * MiB);  // [D x N] fp16 (live until AV)
  float*    part0  = (float*)   (w + 0   * MiB);  // [N x D] fp32 (reuses xq/Wqk/qk)
  float*    part1  = (float*)   (w + 16  * MiB);  // [N x D] fp32 (reuses qk)

  // 1) fused quantization + transpose-cast
  quant_all<<<1572864 / 256, 256, 0, stream>>>(x, Wq, Wk, xq_hi, xq_lo,
                                               Wqk_hi, Wqk_lo);
  transpose_cast_f16<<<dim3(D / 32, N / 32), dim3(32, 32), 0, stream>>>(x, xTh);

  // 2) fused qk projection: i8 32x32, 3-MFMA, bias+quant epilogue
  gemm_i8_32<1><<<dim3(2048 / 128, N / 128), 256, 0, stream>>>(
      xq_hi, xq_lo, Wqk_hi, Wqk_lo, bq, bk, qk_hi, qk_lo,
      /*lda=*/D, /*ldb=*/D, /*ldc=*/2048, /*K=*/D, P_HH, P_X);

  // 3) S = q k^T: i8 32x32, 3-MFMA, fp32 out
  gemm_i8_32<0><<<dim3(N / 128, N / 128), 256, 0, stream>>>(
      qk_hi, qk_lo, qk_hi + 1024, qk_lo + 1024, nullptr, nullptr, S, nullptr,
      /*lda=*/2048, /*ldb=*/2048, /*ldc=*/N, /*K=*/D, C_HH, C_X);

  // 4) softmax rows, attn fp16 in-place into S rows (stride 8192 uint16)
  softmax_rows<<<N, 1024, 0, stream>>>(S);

  // 5) out = attn * x, fp16, split-K=2, XCD-swizzled linear grid
  gemm_av<<<512, 256, 0, stream>>>((const uint16_t*)S, xTh, part0);

  // 6) reduce partials (gemm_av wrote z=1 at part0 + 16 MiB = part1)
  add2<<<N * D / 4 / 256, 256, 0, stream>>>(part0, part1, out, N * D / 4);

  (void)in_sizes; (void)n_in; (void)out_size; (void)ws_size;
}

// Round 7
// 250.668 us; speedup vs baseline: 1.3914x; 1.3914x over previous
//
#include <hip/hip_runtime.h>
#include <hip/hip_bf16.h>
#include <hip/hip_fp16.h>
#include <stdint.h>

// ---------------------------------------------------------------------------
// CLIPAttentionPooling. R7: revert R6's 32x32 experiment (latency-stalled:
// BK=32 doubled barrier rate, 4-tile ILP starved the MFMA pipe). S and proj
// both use the R4/R5-verified 16x16x64 i8 split kernel (128x128 tile, BK=64,
// 16 independent accum tiles). Proj drops the lo*lo plane (4->3 MFMAs,
// dropped term ~ quant-grid lsb). Fused quant; attn fp16 in-place in S rows;
// AV fp16 with XCD swizzle + split-K=2.
// ---------------------------------------------------------------------------

using short8  = __attribute__((ext_vector_type(8))) short;
using half8   = __attribute__((ext_vector_type(8))) _Float16;
using float4v = __attribute__((ext_vector_type(4))) float;
using int4v   = __attribute__((ext_vector_type(4))) int;

// q/k int16 grid: covers +-6.0, v = QS*(256*hi+lo)
#define QS        (6.0f / 32768.0f)
#define INV_S     (32768.0f / 6.0f)
#define INV_S256  (128.0f / 6.0f)
#define C_HH      (65536.0f * QS * QS)
#define C_X       (256.0f * QS * QS)

// x grid: +-6.0 ; W grid: +-0.25
#define SX        (6.0f / 32768.0f)
#define SW        (0.25f / 32768.0f)
#define P_HH      (65536.0f * SX * SW)
#define P_X       (256.0f * SX * SW)

#define GLOAD_LDS16(gptr, ldsptr)                                              \
  __builtin_amdgcn_global_load_lds(                                            \
      (__attribute__((address_space(1))) void*)(uintptr_t)(gptr),              \
      (__attribute__((address_space(3))) void*)(unsigned)(uintptr_t)(ldsptr),  \
      16, 0, 0)

// ---------------------------------------------------------------------------
// Split-i8 GEMM, 16x16x64 MFMA, 128x128 tile, BK=64 (R4/R5-verified).
// C = c_hh*(Ahi Bhi^T) + c_x*(Ahi Blo^T + Alo Bhi^T)   [lo*lo dropped]
// EPI=0: store fp32 to Ch.  EPI=1: add bias (biasQ cols<1024 else biasK),
//        re-quantize to int16 grid, store i8 hi/lo planes to Ch/Cl.
template <int EPI>
__global__ __launch_bounds__(256, 2) void gemm_i8(
    const int8_t* __restrict__ Ahi, const int8_t* __restrict__ Alo,
    const int8_t* __restrict__ Bhi, const int8_t* __restrict__ Blo,
    const float* __restrict__ biasQ, const float* __restrict__ biasK,
    void* __restrict__ Ch, void* __restrict__ Cl,
    int lda, int ldb, int ldc, int K, float c_hh, float c_x)
{
  __shared__ __align__(16) int8_t sAh[128 * 64];
  __shared__ __align__(16) int8_t sAl[128 * 64];
  __shared__ __align__(16) int8_t sBh[128 * 64];
  __shared__ __align__(16) int8_t sBl[128 * 64];

  const int tid  = threadIdx.x;
  const int wave = tid >> 6;
  const int lane = tid & 63;
  const int quad = lane >> 4;
  const int t16  = lane & 15;
  const int wm   = wave & 1;
  const int wn   = wave >> 1;
  const int row0 = blockIdx.y * 128;
  const int col0 = blockIdx.x * 128;

  const int seg  = lane & 3;   // 16B segment within a 64-byte row
  const int rsub = lane >> 2;  // row within this wave's 16-row chunk

  int4v hh[4][4], cc[4][4];
#pragma unroll
  for (int i = 0; i < 4; ++i)
#pragma unroll
    for (int j = 0; j < 4; ++j) {
      hh[i][j] = (int4v){0, 0, 0, 0};
      cc[i][j] = (int4v){0, 0, 0, 0};
    }

  for (int k0 = 0; k0 < K; k0 += 64) {
#pragma unroll
    for (int r = 0; r < 2; ++r) {
      const int trow = r * 64 + wave * 16;
      const size_t goffA = (size_t)(row0 + trow + rsub) * lda + k0 + seg * 16;
      const size_t goffB = (size_t)(col0 + trow + rsub) * ldb + k0 + seg * 16;
      GLOAD_LDS16(Ahi + goffA, &sAh[trow * 64]);
      GLOAD_LDS16(Alo + goffA, &sAl[trow * 64]);
      GLOAD_LDS16(Bhi + goffB, &sBh[trow * 64]);
      GLOAD_LDS16(Blo + goffB, &sBl[trow * 64]);
    }
    __syncthreads();

    // i8 16x16x64 frag: lane holds [m=lane&15][k=quad*16+0..15] (verified R4)
    int4v ah[4], al[4], bh[4], bl[4];
#pragma unroll
    for (int i = 0; i < 4; ++i) {
      const int ar = (wm * 64 + i * 16 + t16) * 64 + quad * 16;
      ah[i] = *(const int4v*)&sAh[ar];
      al[i] = *(const int4v*)&sAl[ar];
    }
#pragma unroll
    for (int j = 0; j < 4; ++j) {
      const int br = (wn * 64 + j * 16 + t16) * 64 + quad * 16;
      bh[j] = *(const int4v*)&sBh[br];
      bl[j] = *(const int4v*)&sBl[br];
    }

#pragma unroll
    for (int i = 0; i < 4; ++i)
#pragma unroll
      for (int j = 0; j < 4; ++j) {
        hh[i][j] = __builtin_amdgcn_mfma_i32_16x16x64_i8(ah[i], bh[j], hh[i][j], 0, 0, 0);
        cc[i][j] = __builtin_amdgcn_mfma_i32_16x16x64_i8(ah[i], bl[j], cc[i][j], 0, 0, 0);
        cc[i][j] = __builtin_amdgcn_mfma_i32_16x16x64_i8(al[i], bh[j], cc[i][j], 0, 0, 0);
      }
    __syncthreads();
  }

  // epilogue: C/D layout col = lane&15, row = quad*4 + r  [verified m89]
#pragma unroll
  for (int i = 0; i < 4; ++i) {
#pragma unroll
    for (int j = 0; j < 4; ++j) {
      const int ccol = col0 + wn * 64 + j * 16 + t16;
      const float* bp = nullptr;
      if (EPI == 1) bp = (ccol < 1024) ? biasQ : (biasK - 1024);
#pragma unroll
      for (int r = 0; r < 4; ++r) {
        const int crow = row0 + wm * 64 + i * 16 + quad * 4 + r;
        float v = c_hh * (float)hh[i][j][r] + c_x * (float)cc[i][j][r];
        if (EPI == 0) {
          ((float*)Ch)[(size_t)crow * ldc + ccol] = v;
        } else {
          v += bp[ccol];
          int hi = (int)lrintf(v * INV_S256);
          hi = hi > 127 ? 127 : (hi < -127 ? -127 : hi);
          int lo = (int)lrintf(v * INV_S - 256.0f * (float)hi);
          lo = lo > 127 ? 127 : (lo < -127 ? -127 : lo);
          ((int8_t*)Ch)[(size_t)crow * ldc + ccol] = (int8_t)hi;
          ((int8_t*)Cl)[(size_t)crow * ldc + ccol] = (int8_t)lo;
        }
      }
    }
  }
}

// ---------------------------------------------------------------------------
// AV: out_part = attn * x. fp16 MFMA 16x16x32, split-K=2, XCD-aware swizzle:
// all 16 blocks (8 cols x 2 z) of one 128-row attn band share (id mod 8).
__global__ __launch_bounds__(256) void gemm_av(
    const uint16_t* __restrict__ A, const uint16_t* __restrict__ B,
    float* __restrict__ part)
{
  __shared__ uint16_t sA[128 * 32];
  __shared__ uint16_t sB[128 * 32];

  const int L    = blockIdx.x;                 // 0..511
  const int slot = L >> 3;                     // 0..63
  const int band = (L & 7) + 8 * (slot >> 4);  // 0..31
  const int rem  = slot & 15;
  const int xcol = rem & 7;
  const int z    = rem >> 3;

  const int tid  = threadIdx.x;
  const int wave = tid >> 6;
  const int lane = tid & 63;
  const int quad = lane >> 4;
  const int t16  = lane & 15;
  const int wm   = wave & 1;
  const int wn   = wave >> 1;
  const int row0 = band * 128;
  const int col0 = xcol * 128;

  const int seg  = lane & 3;
  const int rsub = lane >> 2;

  float4v acc[4][4];
#pragma unroll
  for (int i = 0; i < 4; ++i)
#pragma unroll
    for (int j = 0; j < 4; ++j)
      acc[i][j] = (float4v){0.f, 0.f, 0.f, 0.f};

  const int k_begin = z * 2048, k_end = k_begin + 2048;
  for (int k0 = k_begin; k0 < k_end; k0 += 32) {
#pragma unroll
    for (int r = 0; r < 2; ++r) {
      const int trow = r * 64 + wave * 16;
      const size_t goffA = (size_t)(row0 + trow + rsub) * 8192 + k0 + seg * 8;
      const size_t goffB = (size_t)(col0 + trow + rsub) * 4096 + k0 + seg * 8;
      GLOAD_LDS16(A + goffA, &sA[trow * 32]);
      GLOAD_LDS16(B + goffB, &sB[trow * 32]);
    }
    __syncthreads();

    half8 af[4], bf[4];
#pragma unroll
    for (int i = 0; i < 4; ++i)
      af[i] = *(const half8*)&sA[(wm * 64 + i * 16 + t16) * 32 + quad * 8];
#pragma unroll
    for (int j = 0; j < 4; ++j)
      bf[j] = *(const half8*)&sB[(wn * 64 + j * 16 + t16) * 32 + quad * 8];

#pragma unroll
    for (int i = 0; i < 4; ++i)
#pragma unroll
      for (int j = 0; j < 4; ++j)
        acc[i][j] = __builtin_amdgcn_mfma_f32_16x16x32_f16(af[i], bf[j], acc[i][j], 0, 0, 0);
    __syncthreads();
  }

#pragma unroll
  for (int i = 0; i < 4; ++i) {
#pragma unroll
    for (int j = 0; j < 4; ++j) {
      const int ccol = col0 + wn * 64 + j * 16 + t16;
#pragma unroll
      for (int r = 0; r < 4; ++r) {
        const int crow = row0 + wm * 64 + i * 16 + quad * 4 + r;
        part[(size_t)z * 4096 * 1024 + (size_t)crow * 1024 + ccol] = acc[i][j][r];
      }
    }
  }
}

// ---------------------------------------------------------------------------
// One fused quantizer: x (1M float4s, +-6 grid) then Wq, Wk (262144 each,
// +-0.25 grid) into i8 hi/lo planes. Wk planes at offset D*D.
__global__ __launch_bounds__(256) void quant_all(
    const float* __restrict__ x, const float* __restrict__ Wq,
    const float* __restrict__ Wk,
    int8_t* __restrict__ xhi, int8_t* __restrict__ xlo,
    int8_t* __restrict__ whi, int8_t* __restrict__ wlo)
{
  int i = blockIdx.x * blockDim.x + threadIdx.x;  // 0..1572863
  const float* src; int8_t* dh; int8_t* dl; int idx; float s256, s;
  if (i < 1048576)      { src = x;  idx = i;           dh = xhi; dl = xlo;
                          s256 = INV_S256; s = INV_S; }
  else if (i < 1310720) { src = Wq; idx = i - 1048576; dh = whi; dl = wlo;
                          s256 = 512.0f; s = 131072.0f; }
  else                  { src = Wk; idx = i - 1310720; dh = whi + 1048576;
                          dl = wlo + 1048576; s256 = 512.0f; s = 131072.0f; }
  float4 v = ((const float4*)src)[idx];
  float vv[4] = {v.x, v.y, v.z, v.w};
  int hp = 0, lp = 0;
#pragma unroll
  for (int c = 0; c < 4; ++c) {
    int h = (int)lrintf(vv[c] * s256);
    h = h > 127 ? 127 : (h < -127 ? -127 : h);
    int l = (int)lrintf(vv[c] * s - 256.0f * (float)h);
    l = l > 127 ? 127 : (l < -127 ? -127 : l);
    hp |= (h & 0xff) << (8 * c);
    lp |= (l & 0xff) << (8 * c);
  }
  ((int*)dh)[idx] = hp;
  ((int*)dl)[idx] = lp;
}

// x [4096 x 1024] fp32 -> xT [1024 x 4096] fp16
__global__ __launch_bounds__(1024) void transpose_cast_f16(
    const float* __restrict__ x, uint16_t* __restrict__ xT)
{
  __shared__ float tile[32][33];
  const int tx = threadIdx.x, ty = threadIdx.y;
  const int col = blockIdx.x * 32 + tx;
  const int row = blockIdx.y * 32 + ty;
  tile[ty][tx] = x[(size_t)row * 1024 + col];
  __syncthreads();
  __half h = __float2half_rn(tile[tx][ty]);
  xT[(size_t)(blockIdx.x * 32 + ty) * 4096 + blockIdx.y * 32 + tx] = *(uint16_t*)&h;
}

// per-row softmax over S fp32 [4096 x 4096]; attn fp16 written in-place into
// the first half of each 16 KB S row.
__global__ __launch_bounds__(1024) void softmax_rows(float* __restrict__ S)
{
  const int row = blockIdx.x;
  const size_t base = (size_t)row * 4096;
  const int tid = threadIdx.x;
  const int wid = tid >> 6, lane = tid & 63;
  __shared__ float red[16];

  float4 v = ((const float4*)(S + base))[tid];
  float m = fmaxf(fmaxf(v.x, v.y), fmaxf(v.z, v.w));
#pragma unroll
  for (int off = 32; off; off >>= 1) m = fmaxf(m, __shfl_xor(m, off));
  if (lane == 0) red[wid] = m;
  __syncthreads();
  float mall = red[0];
#pragma unroll
  for (int i = 1; i < 16; ++i) mall = fmaxf(mall, red[i]);

  float4 e;
  e.x = __expf(v.x - mall);
  e.y = __expf(v.y - mall);
  e.z = __expf(v.z - mall);
  e.w = __expf(v.w - mall);
  float s = e.x + e.y + e.z + e.w;
#pragma unroll
  for (int off = 32; off; off >>= 1) s += __shfl_xor(s, off);
  __syncthreads();
  if (lane == 0) red[wid] = s;
  __syncthreads();
  float sall = 0.f;
#pragma unroll
  for (int i = 0; i < 16; ++i) sall += red[i];
  const float inv = 1.0f / sall;

  union { __half h[4]; short4 s4; } u;
  u.h[0] = __float2half_rn(e.x * inv);
  u.h[1] = __float2half_rn(e.y * inv);
  u.h[2] = __float2half_rn(e.z * inv);
  u.h[3] = __float2half_rn(e.w * inv);
  ((short4*)S)[(size_t)row * 2048 + tid] = u.s4;
}

// out = p0 + p1 (split-K reduce)
__global__ __launch_bounds__(256) void add2(
    const float* __restrict__ p0, const float* __restrict__ p1,
    float* __restrict__ out, int n4)
{
  int i = blockIdx.x * blockDim.x + threadIdx.x;
  if (i < n4) {
    float4 a = ((const float4*)p0)[i];
    float4 b = ((const float4*)p1)[i];
    float4 o = {a.x + b.x, a.y + b.y, a.z + b.z, a.w + b.w};
    ((float4*)out)[i] = o;
  }
}

extern "C" void kernel_launch(void* const* d_in, const int* in_sizes, int n_in,
                              void* d_out, int out_size, void* d_ws, size_t ws_size,
                              hipStream_t stream) {
  const int N = 4096, D = 1024;
  const float* x  = (const float*)d_in[0];
  const float* Wq = (const float*)d_in[1];
  const float* bq = (const float*)d_in[2];
  const float* Wk = (const float*)d_in[3];
  const float* bk = (const float*)d_in[4];
  float* out = (float*)d_out;

  // workspace layout (MiB offsets), total 108 MiB
  char* w = (char*)d_ws;
  const size_t MiB = 1024 * 1024;
  int8_t*   xq_hi  = (int8_t*)  (w + 0   * MiB);  // [N x D]      (dead after proj)
  int8_t*   xq_lo  = (int8_t*)  (w + 4   * MiB);
  int8_t*   Wqk_hi = (int8_t*)  (w + 8   * MiB);  // [2048 x D]   (dead after proj)
  int8_t*   Wqk_lo = (int8_t*)  (w + 10  * MiB);
  int8_t*   qk_hi  = (int8_t*)  (w + 12  * MiB);  // [N x 2048]   (dead after S)
  int8_t*   qk_lo  = (int8_t*)  (w + 20  * MiB);
  float*    S      = (float*)   (w + 36  * MiB);  // [N x N] fp32, 64 MiB
  uint16_t* xTh    = (uint16_t*)(w + 100 * MiB);  // [D x N] fp16 (live until AV)
  float*    part0  = (float*)   (w + 0   * MiB);  // [N x D] fp32 (reuses xq/Wqk/qk)
  float*    part1  = (float*)   (w + 16  * MiB);  // [N x D] fp32 (reuses qk)

  // 1) fused quantization + transpose-cast
  quant_all<<<1572864 / 256, 256, 0, stream>>>(x, Wq, Wk, xq_hi, xq_lo,
                                               Wqk_hi, Wqk_lo);
  transpose_cast_f16<<<dim3(D / 32, N / 32), dim3(32, 32), 0, stream>>>(x, xTh);

  // 2) fused qk projection: i8 16x16x64, 3-MFMA, bias+quant epilogue
  gemm_i8<1><<<dim3(2048 / 128, N / 128), 256, 0, stream>>>(
      xq_hi, xq_lo, Wqk_hi, Wqk_lo, bq, bk, qk_hi, qk_lo,
      /*lda=*/D, /*ldb=*/D, /*ldc=*/2048, /*K=*/D, P_HH, P_X);

  // 3) S = q k^T: i8 16x16x64, 3-MFMA, fp32 out
  gemm_i8<0><<<dim3(N / 128, N / 128), 256, 0, stream>>>(
      qk_hi, qk_lo, qk_hi + 1024, qk_lo + 1024, nullptr, nullptr, S, nullptr,
      /*lda=*/2048, /*ldb=*/2048, /*ldc=*/N, /*K=*/D, C_HH, C_X);

  // 4) softmax rows, attn fp16 in-place into S rows (stride 8192 uint16)
  softmax_rows<<<N, 1024, 0, stream>>>(S);

  // 5) out = attn * x, fp16, split-K=2, XCD-swizzled linear grid
  gemm_av<<<512, 256, 0, stream>>>((const uint16_t*)S, xTh, part0);

  // 6) reduce partials (gemm_av wrote z=1 at part0 + 16 MiB = part1)
  add2<<<N * D / 4 / 256, 256, 0, stream>>>(part0, part1, out, N * D / 4);

  (void)in_sizes; (void)n_in; (void)out_size; (void)ws_size;
}

// Round 8
// 247.933 us; speedup vs baseline: 1.4068x; 1.0110x over previous
//
#include <hip/hip_runtime.h>
#include <hip/hip_bf16.h>
#include <hip/hip_fp16.h>
#include <stdint.h>

// ---------------------------------------------------------------------------
// CLIPAttentionPooling. R8: fuse softmax stats into the S GEMM epilogue
// (flash-style two-pass): S kernel writes E = exp(S - m_tile) as fp16 (32 MB
// vs 64 MB fp32) + per-(row,tile) stats (m_t, l_t); tiny reduce kernel makes
// beta[row][t] = exp(m_t - m)/l; AV GEMM scales its A-fragment by beta
// (packed f16 mul, hoisted per 128-K tile). Removes the 96 MB softmax pass.
// S/proj: split-i8 16x16x64, BK=64 (R4/R5-verified). AV fp16 + XCD swizzle
// + split-K=2.
// ---------------------------------------------------------------------------

using half8   = __attribute__((ext_vector_type(8))) _Float16;
using float4v = __attribute__((ext_vector_type(4))) float;
using int4v   = __attribute__((ext_vector_type(4))) int;

// q/k int16 grid: covers +-6.0, v = QS*(256*hi+lo)
#define QS        (6.0f / 32768.0f)
#define INV_S     (32768.0f / 6.0f)
#define INV_S256  (128.0f / 6.0f)
#define C_HH      (65536.0f * QS * QS)
#define C_X       (256.0f * QS * QS)

// x grid: +-6.0 ; W grid: +-0.25
#define SX        (6.0f / 32768.0f)
#define SW        (0.25f / 32768.0f)
#define P_HH      (65536.0f * SX * SW)
#define P_X       (256.0f * SX * SW)

#define GLOAD_LDS16(gptr, ldsptr)                                              \
  __builtin_amdgcn_global_load_lds(                                            \
      (__attribute__((address_space(1))) void*)(uintptr_t)(gptr),              \
      (__attribute__((address_space(3))) void*)(unsigned)(uintptr_t)(ldsptr),  \
      16, 0, 0)

// ---------------------------------------------------------------------------
// S GEMM + tile softmax stats. Split-i8 16x16x64, 128x128 tile, BK=64.
// S = C_HH*(Ahi Bhi^T) + C_X*(Ahi Blo^T + Alo Bhi^T)   [lo*lo dropped]
// Epilogue: per tile, row max m_t over 128 cols, E = exp(S - m_t) -> fp16,
// l_t = row sum of E; stats[(row)*32 + tileCol] = (m_t, l_t).
__global__ __launch_bounds__(256, 2) void gemm_s_stats(
    const int8_t* __restrict__ Ahi, const int8_t* __restrict__ Alo,
    const int8_t* __restrict__ Bhi, const int8_t* __restrict__ Blo,
    _Float16* __restrict__ E, float2* __restrict__ stats)
{
  __shared__ __align__(16) int8_t sAh[128 * 64];
  __shared__ __align__(16) int8_t sAl[128 * 64];
  __shared__ __align__(16) int8_t sBh[128 * 64];
  __shared__ __align__(16) int8_t sBl[128 * 64];

  const int tid  = threadIdx.x;
  const int wave = tid >> 6;
  const int lane = tid & 63;
  const int quad = lane >> 4;
  const int t16  = lane & 15;
  const int wm   = wave & 1;
  const int wn   = wave >> 1;
  const int row0 = blockIdx.y * 128;
  const int col0 = blockIdx.x * 128;

  const int seg  = lane & 3;   // 16B segment within a 64-byte row
  const int rsub = lane >> 2;  // row within this wave's 16-row chunk

  int4v hh[4][4], cc[4][4];
#pragma unroll
  for (int i = 0; i < 4; ++i)
#pragma unroll
    for (int j = 0; j < 4; ++j) {
      hh[i][j] = (int4v){0, 0, 0, 0};
      cc[i][j] = (int4v){0, 0, 0, 0};
    }

  for (int k0 = 0; k0 < 1024; k0 += 64) {
#pragma unroll
    for (int r = 0; r < 2; ++r) {
      const int trow = r * 64 + wave * 16;
      const size_t goffA = (size_t)(row0 + trow + rsub) * 2048 + k0 + seg * 16;
      const size_t goffB = (size_t)(col0 + trow + rsub) * 2048 + k0 + seg * 16;
      GLOAD_LDS16(Ahi + goffA, &sAh[trow * 64]);
      GLOAD_LDS16(Alo + goffA, &sAl[trow * 64]);
      GLOAD_LDS16(Bhi + goffB, &sBh[trow * 64]);
      GLOAD_LDS16(Blo + goffB, &sBl[trow * 64]);
    }
    __syncthreads();

    // i8 16x16x64 frag: lane holds [m=lane&15][k=quad*16+0..15] (verified R4)
    int4v ah[4], al[4], bh[4], bl[4];
#pragma unroll
    for (int i = 0; i < 4; ++i) {
      const int ar = (wm * 64 + i * 16 + t16) * 64 + quad * 16;
      ah[i] = *(const int4v*)&sAh[ar];
      al[i] = *(const int4v*)&sAl[ar];
    }
#pragma unroll
    for (int j = 0; j < 4; ++j) {
      const int br = (wn * 64 + j * 16 + t16) * 64 + quad * 16;
      bh[j] = *(const int4v*)&sBh[br];
      bl[j] = *(const int4v*)&sBl[br];
    }

#pragma unroll
    for (int i = 0; i < 4; ++i)
#pragma unroll
      for (int j = 0; j < 4; ++j) {
        hh[i][j] = __builtin_amdgcn_mfma_i32_16x16x64_i8(ah[i], bh[j], hh[i][j], 0, 0, 0);
        cc[i][j] = __builtin_amdgcn_mfma_i32_16x16x64_i8(ah[i], bl[j], cc[i][j], 0, 0, 0);
        cc[i][j] = __builtin_amdgcn_mfma_i32_16x16x64_i8(al[i], bh[j], cc[i][j], 0, 0, 0);
      }
    __syncthreads();
  }

  // ---- epilogue -----------------------------------------------------------
  // value at local (row = wm*64 + i*16 + quad*4 + r, col = wn*64 + j*16 + t16)
  // Reuse staging LDS as float scratch: [0..255] = per-wn row max halves,
  // [256..511] = per-wn row sum halves. (Loop's trailing barrier protects.)
  float* red = (float*)sAh;

  float vv[4][4][4];
  float rmax[4][4];
#pragma unroll
  for (int i = 0; i < 4; ++i)
#pragma unroll
    for (int r = 0; r < 4; ++r) {
      float mx = -3.0e38f;
#pragma unroll
      for (int j = 0; j < 4; ++j) {
        float v = C_HH * (float)hh[i][j][r] + C_X * (float)cc[i][j][r];
        vv[i][j][r] = v;
        mx = fmaxf(mx, v);
      }
      // reduce over the 16 lanes (t16) of this quad — same output row
      mx = fmaxf(mx, __shfl_xor(mx, 1));
      mx = fmaxf(mx, __shfl_xor(mx, 2));
      mx = fmaxf(mx, __shfl_xor(mx, 4));
      mx = fmaxf(mx, __shfl_xor(mx, 8));
      rmax[i][r] = mx;
    }
  if (t16 == 0) {
#pragma unroll
    for (int i = 0; i < 4; ++i)
#pragma unroll
      for (int r = 0; r < 4; ++r)
        red[wn * 128 + wm * 64 + i * 16 + quad * 4 + r] = rmax[i][r];
  }
  __syncthreads();

  float mrow[4][4];
#pragma unroll
  for (int i = 0; i < 4; ++i)
#pragma unroll
    for (int r = 0; r < 4; ++r) {
      const int row = wm * 64 + i * 16 + quad * 4 + r;
      mrow[i][r] = fmaxf(red[row], red[128 + row]);
    }

  float rsum[4][4];
#pragma unroll
  for (int i = 0; i < 4; ++i)
#pragma unroll
    for (int r = 0; r < 4; ++r) {
      float s = 0.f;
#pragma unroll
      for (int j = 0; j < 4; ++j) {
        float e = __expf(vv[i][j][r] - mrow[i][r]);
        vv[i][j][r] = e;
        s += e;
      }
      s += __shfl_xor(s, 1);
      s += __shfl_xor(s, 2);
      s += __shfl_xor(s, 4);
      s += __shfl_xor(s, 8);
      rsum[i][r] = s;
    }
  if (t16 == 0) {
#pragma unroll
    for (int i = 0; i < 4; ++i)
#pragma unroll
      for (int r = 0; r < 4; ++r)
        red[256 + wn * 128 + wm * 64 + i * 16 + quad * 4 + r] = rsum[i][r];
  }
  __syncthreads();

  // E writes (fp16) + one stats writer per row (wn==0, t16==0)
#pragma unroll
  for (int i = 0; i < 4; ++i) {
#pragma unroll
    for (int j = 0; j < 4; ++j) {
#pragma unroll
      for (int r = 0; r < 4; ++r) {
        const int crow = row0 + wm * 64 + i * 16 + quad * 4 + r;
        const int ccol = col0 + wn * 64 + j * 16 + t16;
        E[(size_t)crow * 4096 + ccol] = (_Float16)vv[i][j][r];
      }
    }
  }
  if (wn == 0 && t16 == 0) {
#pragma unroll
    for (int i = 0; i < 4; ++i)
#pragma unroll
      for (int r = 0; r < 4; ++r) {
        const int row = wm * 64 + i * 16 + quad * 4 + r;
        const float l = red[256 + row] + red[256 + 128 + row];
        stats[(size_t)(row0 + row) * 32 + blockIdx.x] =
            make_float2(mrow[i][r], l);
      }
  }
}

// ---------------------------------------------------------------------------
// beta[row][t] = exp(m_t - m) / l,  m = max_t m_t,  l = sum_t l_t exp(m_t - m)
__global__ __launch_bounds__(256) void stats_reduce(
    const float2* __restrict__ stats, float* __restrict__ beta)
{
  const int row = blockIdx.x * blockDim.x + threadIdx.x;  // 0..4095
  float2 st[32];
  float m = -3.0e38f;
#pragma unroll
  for (int t = 0; t < 32; ++t) {
    st[t] = stats[(size_t)row * 32 + t];
    m = fmaxf(m, st[t].x);
  }
  float l = 0.f;
#pragma unroll
  for (int t = 0; t < 32; ++t) l += st[t].y * __expf(st[t].x - m);
  const float inv = 1.0f / l;
#pragma unroll
  for (int t = 0; t < 32; ++t)
    beta[(size_t)row * 32 + t] = __expf(st[t].x - m) * inv;
}

// ---------------------------------------------------------------------------
// proj: qk = x Wqk^T + bias, split-i8 3-MFMA, bias + int16-grid quant epilogue.
// M=4096, N=2048, K=1024. lda=ldb=1024, ldc=2048.
__global__ __launch_bounds__(256, 2) void gemm_proj_i8(
    const int8_t* __restrict__ Ahi, const int8_t* __restrict__ Alo,
    const int8_t* __restrict__ Bhi, const int8_t* __restrict__ Blo,
    const float* __restrict__ biasQ, const float* __restrict__ biasK,
    int8_t* __restrict__ Ch, int8_t* __restrict__ Cl)
{
  __shared__ __align__(16) int8_t sAh[128 * 64];
  __shared__ __align__(16) int8_t sAl[128 * 64];
  __shared__ __align__(16) int8_t sBh[128 * 64];
  __shared__ __align__(16) int8_t sBl[128 * 64];

  const int tid  = threadIdx.x;
  const int wave = tid >> 6;
  const int lane = tid & 63;
  const int quad = lane >> 4;
  const int t16  = lane & 15;
  const int wm   = wave & 1;
  const int wn   = wave >> 1;
  const int row0 = blockIdx.y * 128;
  const int col0 = blockIdx.x * 128;

  const int seg  = lane & 3;
  const int rsub = lane >> 2;

  int4v hh[4][4], cc[4][4];
#pragma unroll
  for (int i = 0; i < 4; ++i)
#pragma unroll
    for (int j = 0; j < 4; ++j) {
      hh[i][j] = (int4v){0, 0, 0, 0};
      cc[i][j] = (int4v){0, 0, 0, 0};
    }

  for (int k0 = 0; k0 < 1024; k0 += 64) {
#pragma unroll
    for (int r = 0; r < 2; ++r) {
      const int trow = r * 64 + wave * 16;
      const size_t goffA = (size_t)(row0 + trow + rsub) * 1024 + k0 + seg * 16;
      const size_t goffB = (size_t)(col0 + trow + rsub) * 1024 + k0 + seg * 16;
      GLOAD_LDS16(Ahi + goffA, &sAh[trow * 64]);
      GLOAD_LDS16(Alo + goffA, &sAl[trow * 64]);
      GLOAD_LDS16(Bhi + goffB, &sBh[trow * 64]);
      GLOAD_LDS16(Blo + goffB, &sBl[trow * 64]);
    }
    __syncthreads();

    int4v ah[4], al[4], bh[4], bl[4];
#pragma unroll
    for (int i = 0; i < 4; ++i) {
      const int ar = (wm * 64 + i * 16 + t16) * 64 + quad * 16;
      ah[i] = *(const int4v*)&sAh[ar];
      al[i] = *(const int4v*)&sAl[ar];
    }
#pragma unroll
    for (int j = 0; j < 4; ++j) {
      const int br = (wn * 64 + j * 16 + t16) * 64 + quad * 16;
      bh[j] = *(const int4v*)&sBh[br];
      bl[j] = *(const int4v*)&sBl[br];
    }

#pragma unroll
    for (int i = 0; i < 4; ++i)
#pragma unroll
      for (int j = 0; j < 4; ++j) {
        hh[i][j] = __builtin_amdgcn_mfma_i32_16x16x64_i8(ah[i], bh[j], hh[i][j], 0, 0, 0);
        cc[i][j] = __builtin_amdgcn_mfma_i32_16x16x64_i8(ah[i], bl[j], cc[i][j], 0, 0, 0);
        cc[i][j] = __builtin_amdgcn_mfma_i32_16x16x64_i8(al[i], bh[j], cc[i][j], 0, 0, 0);
      }
    __syncthreads();
  }

#pragma unroll
  for (int i = 0; i < 4; ++i) {
#pragma unroll
    for (int j = 0; j < 4; ++j) {
      const int ccol = col0 + wn * 64 + j * 16 + t16;
      const float* bp = (ccol < 1024) ? biasQ : (biasK - 1024);
#pragma unroll
      for (int r = 0; r < 4; ++r) {
        const int crow = row0 + wm * 64 + i * 16 + quad * 4 + r;
        float v = P_HH * (float)hh[i][j][r] + P_X * (float)cc[i][j][r] + bp[ccol];
        int hi = (int)lrintf(v * INV_S256);
        hi = hi > 127 ? 127 : (hi < -127 ? -127 : hi);
        int lo = (int)lrintf(v * INV_S - 256.0f * (float)hi);
        lo = lo > 127 ? 127 : (lo < -127 ? -127 : lo);
        Ch[(size_t)crow * 2048 + ccol] = (int8_t)hi;
        Cl[(size_t)crow * 2048 + ccol] = (int8_t)lo;
      }
    }
  }
}

// ---------------------------------------------------------------------------
// AV: out_part = sum_t beta_t (E_t x). fp16 MFMA 16x16x32, split-K=2,
// XCD-aware swizzle. A = E fp16 [4096][4096]; beta applied to A-frags
// (constant per frag-row per 128-K tile, hoisted).
__global__ __launch_bounds__(256) void gemm_av(
    const uint16_t* __restrict__ A, const uint16_t* __restrict__ B,
    const float* __restrict__ beta, float* __restrict__ part)
{
  __shared__ uint16_t sA[128 * 32];
  __shared__ uint16_t sB[128 * 32];

  const int L    = blockIdx.x;                 // 0..511
  const int slot = L >> 3;                     // 0..63
  const int band = (L & 7) + 8 * (slot >> 4);  // 0..31
  const int rem  = slot & 15;
  const int xcol = rem & 7;
  const int z    = rem >> 3;

  const int tid  = threadIdx.x;
  const int wave = tid >> 6;
  const int lane = tid & 63;
  const int quad = lane >> 4;
  const int t16  = lane & 15;
  const int wm   = wave & 1;
  const int wn   = wave >> 1;
  const int row0 = band * 128;
  const int col0 = xcol * 128;

  const int seg  = lane & 3;
  const int rsub = lane >> 2;

  float4v acc[4][4];
#pragma unroll
  for (int i = 0; i < 4; ++i)
#pragma unroll
    for (int j = 0; j < 4; ++j)
      acc[i][j] = (float4v){0.f, 0.f, 0.f, 0.f};

  const int t_begin = z * 16;
  for (int t = t_begin; t < t_begin + 16; ++t) {
    // beta for this 128-K tile, per frag row (A-frag row = lane&15 pattern)
    _Float16 bb[4];
#pragma unroll
    for (int i = 0; i < 4; ++i)
      bb[i] = (_Float16)beta[(size_t)(row0 + wm * 64 + i * 16 + t16) * 32 + t];

#pragma unroll
    for (int kk = 0; kk < 4; ++kk) {
      const int k0 = t * 128 + kk * 32;
#pragma unroll
      for (int r = 0; r < 2; ++r) {
        const int trow = r * 64 + wave * 16;
        const size_t goffA = (size_t)(row0 + trow + rsub) * 4096 + k0 + seg * 8;
        const size_t goffB = (size_t)(col0 + trow + rsub) * 4096 + k0 + seg * 8;
        GLOAD_LDS16(A + goffA, &sA[trow * 32]);
        GLOAD_LDS16(B + goffB, &sB[trow * 32]);
      }
      __syncthreads();

      half8 af[4], bf[4];
#pragma unroll
      for (int i = 0; i < 4; ++i) {
        af[i] = *(const half8*)&sA[(wm * 64 + i * 16 + t16) * 32 + quad * 8];
        half8 bs;
#pragma unroll
        for (int c = 0; c < 8; ++c) bs[c] = bb[i];
        af[i] = af[i] * bs;
      }
#pragma unroll
      for (int j = 0; j < 4; ++j)
        bf[j] = *(const half8*)&sB[(wn * 64 + j * 16 + t16) * 32 + quad * 8];

#pragma unroll
      for (int i = 0; i < 4; ++i)
#pragma unroll
        for (int j = 0; j < 4; ++j)
          acc[i][j] = __builtin_amdgcn_mfma_f32_16x16x32_f16(af[i], bf[j], acc[i][j], 0, 0, 0);
      __syncthreads();
    }
  }

#pragma unroll
  for (int i = 0; i < 4; ++i) {
#pragma unroll
    for (int j = 0; j < 4; ++j) {
      const int ccol = col0 + wn * 64 + j * 16 + t16;
#pragma unroll
      for (int r = 0; r < 4; ++r) {
        const int crow = row0 + wm * 64 + i * 16 + quad * 4 + r;
        part[(size_t)z * 4096 * 1024 + (size_t)crow * 1024 + ccol] = acc[i][j][r];
      }
    }
  }
}

// ---------------------------------------------------------------------------
// One fused quantizer: x (1M float4s, +-6 grid) then Wq, Wk (+-0.25 grid).
__global__ __launch_bounds__(256) void quant_all(
    const float* __restrict__ x, const float* __restrict__ Wq,
    const float* __restrict__ Wk,
    int8_t* __restrict__ xhi, int8_t* __restrict__ xlo,
    int8_t* __restrict__ whi, int8_t* __restrict__ wlo)
{
  int i = blockIdx.x * blockDim.x + threadIdx.x;  // 0..1572863
  const float* src; int8_t* dh; int8_t* dl; int idx; float s256, s;
  if (i < 1048576)      { src = x;  idx = i;           dh = xhi; dl = xlo;
                          s256 = INV_S256; s = INV_S; }
  else if (i < 1310720) { src = Wq; idx = i - 1048576; dh = whi; dl = wlo;
                          s256 = 512.0f; s = 131072.0f; }
  else                  { src = Wk; idx = i - 1310720; dh = whi + 1048576;
                          dl = wlo + 1048576; s256 = 512.0f; s = 131072.0f; }
  float4 v = ((const float4*)src)[idx];
  float vv[4] = {v.x, v.y, v.z, v.w};
  int hp = 0, lp = 0;
#pragma unroll
  for (int c = 0; c < 4; ++c) {
    int h = (int)lrintf(vv[c] * s256);
    h = h > 127 ? 127 : (h < -127 ? -127 : h);
    int l = (int)lrintf(vv[c] * s - 256.0f * (float)h);
    l = l > 127 ? 127 : (l < -127 ? -127 : l);
    hp |= (h & 0xff) << (8 * c);
    lp |= (l & 0xff) << (8 * c);
  }
  ((int*)dh)[idx] = hp;
  ((int*)dl)[idx] = lp;
}

// x [4096 x 1024] fp32 -> xT [1024 x 4096] fp16
__global__ __launch_bounds__(1024) void transpose_cast_f16(
    const float* __restrict__ x, uint16_t* __restrict__ xT)
{
  __shared__ float tile[32][33];
  const int tx = threadIdx.x, ty = threadIdx.y;
  const int col = blockIdx.x * 32 + tx;
  const int row = blockIdx.y * 32 + ty;
  tile[ty][tx] = x[(size_t)row * 1024 + col];
  __syncthreads();
  __half h = __float2half_rn(tile[tx][ty]);
  xT[(size_t)(blockIdx.x * 32 + ty) * 4096 + blockIdx.y * 32 + tx] = *(uint16_t*)&h;
}

// out = p0 + p1 (split-K reduce)
__global__ __launch_bounds__(256) void add2(
    const float* __restrict__ p0, const float* __restrict__ p1,
    float* __restrict__ out, int n4)
{
  int i = blockIdx.x * blockDim.x + threadIdx.x;
  if (i < n4) {
    float4 a = ((const float4*)p0)[i];
    float4 b = ((const float4*)p1)[i];
    float4 o = {a.x + b.x, a.y + b.y, a.z + b.z, a.w + b.w};
    ((float4*)out)[i] = o;
  }
}

extern "C" void kernel_launch(void* const* d_in, const int* in_sizes, int n_in,
                              void* d_out, int out_size, void* d_ws, size_t ws_size,
                              hipStream_t stream) {
  const int N = 4096, D = 1024;
  const float* x  = (const float*)d_in[0];
  const float* Wq = (const float*)d_in[1];
  const float* bq = (const float*)d_in[2];
  const float* Wk = (const float*)d_in[3];
  const float* bk = (const float*)d_in[4];
  float* out = (float*)d_out;

  // workspace layout (MiB offsets)
  char* w = (char*)d_ws;
  const size_t MiB = 1024 * 1024;
  int8_t*    xq_hi  = (int8_t*)   (w + 0  * MiB);  // [N x D]     (dead after proj)
  int8_t*    xq_lo  = (int8_t*)   (w + 4  * MiB);
  int8_t*    Wqk_hi = (int8_t*)   (w + 8  * MiB);  // [2048 x D]  (dead after proj)
  int8_t*    Wqk_lo = (int8_t*)   (w + 10 * MiB);
  int8_t*    qk_hi  = (int8_t*)   (w + 12 * MiB);  // [N x 2048]  (dead after S)
  int8_t*    qk_lo  = (int8_t*)   (w + 20 * MiB);
  _Float16*  E      = (_Float16*) (w + 36 * MiB);  // [N x N] fp16, 32 MiB
  float2*    stats  = (float2*)   (w + 68 * MiB);  // [N x 32] (m,l), 1 MiB
  float*     beta   = (float*)    (w + 70 * MiB);  // [N x 32], 0.5 MiB
  uint16_t*  xTh    = (uint16_t*) (w + 72 * MiB);  // [D x N] fp16 (live until AV)
  float*     part0  = (float*)    (w + 0  * MiB);  // [N x D] fp32 (reuses xq/Wqk)
  float*     part1  = (float*)    (w + 16 * MiB);  // [N x D] fp32 (reuses qk)
  // total 80 MiB

  // 1) fused quantization + transpose-cast
  quant_all<<<1572864 / 256, 256, 0, stream>>>(x, Wq, Wk, xq_hi, xq_lo,
                                               Wqk_hi, Wqk_lo);
  transpose_cast_f16<<<dim3(D / 32, N / 32), dim3(32, 32), 0, stream>>>(x, xTh);

  // 2) fused qk projection: i8 16x16x64, 3-MFMA, bias+quant epilogue
  gemm_proj_i8<<<dim3(2048 / 128, N / 128), 256, 0, stream>>>(
      xq_hi, xq_lo, Wqk_hi, Wqk_lo, bq, bk, qk_hi, qk_lo);

  // 3) S = q k^T + tile softmax stats -> E fp16, stats (m_t, l_t)
  gemm_s_stats<<<dim3(N / 128, N / 128), 256, 0, stream>>>(
      qk_hi, qk_lo, qk_hi + 1024, qk_lo + 1024, E, stats);

  // 4) reduce stats -> beta[row][t]
  stats_reduce<<<N / 256, 256, 0, stream>>>(stats, beta);

  // 5) out = sum_t beta_t (E_t x), fp16, split-K=2, XCD-swizzled
  gemm_av<<<512, 256, 0, stream>>>((const uint16_t*)E, xTh, beta, part0);

  // 6) reduce partials (gemm_av wrote z=1 at part0 + 16 MiB = part1)
  add2<<<N * D / 4 / 256, 256, 0, stream>>>(part0, part1, out, N * D / 4);

  (void)in_sizes; (void)n_in; (void)out_size; (void)ws_size;
}

// Round 9
// 242.538 us; speedup vs baseline: 1.4380x; 1.0222x over previous
//
#include <hip/hip_runtime.h>
#include <hip/hip_bf16.h>
#include <hip/hip_fp16.h>
#include <stdint.h>

// ---------------------------------------------------------------------------
// CLIPAttentionPooling. R9: launch-count attack (R8 post-mortem: ~65 us in
// dispatch gaps). 8 -> 4 dispatches:
//   1. quantT        : quant x/Wq/Wk to i8 planes + transpose-cast x -> fp16
//   2. gemm_proj_i8  : qk = x Wqk^T + bias, split-i8 3-MFMA, quant epilogue
//   3. gemm_s_stats  : E = exp(S - m_tile) fp16 + (m_t, l_t) stats
//   4. gemm_av       : beta from stats in prologue (LDS), in-block split-K=2
//                      (512 thr, two wave-groups), direct fp32 store to out.
// ---------------------------------------------------------------------------

using half8   = __attribute__((ext_vector_type(8))) _Float16;
using float4v = __attribute__((ext_vector_type(4))) float;
using int4v   = __attribute__((ext_vector_type(4))) int;

// q/k int16 grid: covers +-6.0, v = QS*(256*hi+lo)
#define QS        (6.0f / 32768.0f)
#define INV_S     (32768.0f / 6.0f)
#define INV_S256  (128.0f / 6.0f)
#define C_HH      (65536.0f * QS * QS)
#define C_X       (256.0f * QS * QS)

// x grid: +-6.0 ; W grid: +-0.25
#define SX        (6.0f / 32768.0f)
#define SW        (0.25f / 32768.0f)
#define P_HH      (65536.0f * SX * SW)
#define P_X       (256.0f * SX * SW)

#define GLOAD_LDS16(gptr, ldsptr)                                              \
  __builtin_amdgcn_global_load_lds(                                            \
      (__attribute__((address_space(1))) void*)(uintptr_t)(gptr),              \
      (__attribute__((address_space(3))) void*)(unsigned)(uintptr_t)(ldsptr),  \
      16, 0, 0)

// ---------------------------------------------------------------------------
// S GEMM + tile softmax stats. Split-i8 16x16x64, 128x128 tile, BK=64.
__global__ __launch_bounds__(256, 2) void gemm_s_stats(
    const int8_t* __restrict__ Ahi, const int8_t* __restrict__ Alo,
    const int8_t* __restrict__ Bhi, const int8_t* __restrict__ Blo,
    _Float16* __restrict__ E, float2* __restrict__ stats)
{
  __shared__ __align__(16) int8_t sAh[128 * 64];
  __shared__ __align__(16) int8_t sAl[128 * 64];
  __shared__ __align__(16) int8_t sBh[128 * 64];
  __shared__ __align__(16) int8_t sBl[128 * 64];

  const int tid  = threadIdx.x;
  const int wave = tid >> 6;
  const int lane = tid & 63;
  const int quad = lane >> 4;
  const int t16  = lane & 15;
  const int wm   = wave & 1;
  const int wn   = wave >> 1;
  const int row0 = blockIdx.y * 128;
  const int col0 = blockIdx.x * 128;

  const int seg  = lane & 3;
  const int rsub = lane >> 2;

  int4v hh[4][4], cc[4][4];
#pragma unroll
  for (int i = 0; i < 4; ++i)
#pragma unroll
    for (int j = 0; j < 4; ++j) {
      hh[i][j] = (int4v){0, 0, 0, 0};
      cc[i][j] = (int4v){0, 0, 0, 0};
    }

  for (int k0 = 0; k0 < 1024; k0 += 64) {
#pragma unroll
    for (int r = 0; r < 2; ++r) {
      const int trow = r * 64 + wave * 16;
      const size_t goffA = (size_t)(row0 + trow + rsub) * 2048 + k0 + seg * 16;
      const size_t goffB = (size_t)(col0 + trow + rsub) * 2048 + k0 + seg * 16;
      GLOAD_LDS16(Ahi + goffA, &sAh[trow * 64]);
      GLOAD_LDS16(Alo + goffA, &sAl[trow * 64]);
      GLOAD_LDS16(Bhi + goffB, &sBh[trow * 64]);
      GLOAD_LDS16(Blo + goffB, &sBl[trow * 64]);
    }
    __syncthreads();

    int4v ah[4], al[4], bh[4], bl[4];
#pragma unroll
    for (int i = 0; i < 4; ++i) {
      const int ar = (wm * 64 + i * 16 + t16) * 64 + quad * 16;
      ah[i] = *(const int4v*)&sAh[ar];
      al[i] = *(const int4v*)&sAl[ar];
    }
#pragma unroll
    for (int j = 0; j < 4; ++j) {
      const int br = (wn * 64 + j * 16 + t16) * 64 + quad * 16;
      bh[j] = *(const int4v*)&sBh[br];
      bl[j] = *(const int4v*)&sBl[br];
    }

#pragma unroll
    for (int i = 0; i < 4; ++i)
#pragma unroll
      for (int j = 0; j < 4; ++j) {
        hh[i][j] = __builtin_amdgcn_mfma_i32_16x16x64_i8(ah[i], bh[j], hh[i][j], 0, 0, 0);
        cc[i][j] = __builtin_amdgcn_mfma_i32_16x16x64_i8(ah[i], bl[j], cc[i][j], 0, 0, 0);
        cc[i][j] = __builtin_amdgcn_mfma_i32_16x16x64_i8(al[i], bh[j], cc[i][j], 0, 0, 0);
      }
    __syncthreads();
  }

  // ---- epilogue: tile-local softmax stats (R8-verified) --------------------
  float* red = (float*)sAh;

  float vv[4][4][4];
  float rmax[4][4];
#pragma unroll
  for (int i = 0; i < 4; ++i)
#pragma unroll
    for (int r = 0; r < 4; ++r) {
      float mx = -3.0e38f;
#pragma unroll
      for (int j = 0; j < 4; ++j) {
        float v = C_HH * (float)hh[i][j][r] + C_X * (float)cc[i][j][r];
        vv[i][j][r] = v;
        mx = fmaxf(mx, v);
      }
      mx = fmaxf(mx, __shfl_xor(mx, 1));
      mx = fmaxf(mx, __shfl_xor(mx, 2));
      mx = fmaxf(mx, __shfl_xor(mx, 4));
      mx = fmaxf(mx, __shfl_xor(mx, 8));
      rmax[i][r] = mx;
    }
  if (t16 == 0) {
#pragma unroll
    for (int i = 0; i < 4; ++i)
#pragma unroll
      for (int r = 0; r < 4; ++r)
        red[wn * 128 + wm * 64 + i * 16 + quad * 4 + r] = rmax[i][r];
  }
  __syncthreads();

  float mrow[4][4];
#pragma unroll
  for (int i = 0; i < 4; ++i)
#pragma unroll
    for (int r = 0; r < 4; ++r) {
      const int row = wm * 64 + i * 16 + quad * 4 + r;
      mrow[i][r] = fmaxf(red[row], red[128 + row]);
    }

  float rsum[4][4];
#pragma unroll
  for (int i = 0; i < 4; ++i)
#pragma unroll
    for (int r = 0; r < 4; ++r) {
      float s = 0.f;
#pragma unroll
      for (int j = 0; j < 4; ++j) {
        float e = __expf(vv[i][j][r] - mrow[i][r]);
        vv[i][j][r] = e;
        s += e;
      }
      s += __shfl_xor(s, 1);
      s += __shfl_xor(s, 2);
      s += __shfl_xor(s, 4);
      s += __shfl_xor(s, 8);
      rsum[i][r] = s;
    }
  if (t16 == 0) {
#pragma unroll
    for (int i = 0; i < 4; ++i)
#pragma unroll
      for (int r = 0; r < 4; ++r)
        red[256 + wn * 128 + wm * 64 + i * 16 + quad * 4 + r] = rsum[i][r];
  }
  __syncthreads();

#pragma unroll
  for (int i = 0; i < 4; ++i) {
#pragma unroll
    for (int j = 0; j < 4; ++j) {
#pragma unroll
      for (int r = 0; r < 4; ++r) {
        const int crow = row0 + wm * 64 + i * 16 + quad * 4 + r;
        const int ccol = col0 + wn * 64 + j * 16 + t16;
        E[(size_t)crow * 4096 + ccol] = (_Float16)vv[i][j][r];
      }
    }
  }
  if (wn == 0 && t16 == 0) {
#pragma unroll
    for (int i = 0; i < 4; ++i)
#pragma unroll
      for (int r = 0; r < 4; ++r) {
        const int row = wm * 64 + i * 16 + quad * 4 + r;
        const float l = red[256 + row] + red[256 + 128 + row];
        stats[(size_t)(row0 + row) * 32 + blockIdx.x] =
            make_float2(mrow[i][r], l);
      }
  }
}

// ---------------------------------------------------------------------------
// proj: qk = x Wqk^T + bias, split-i8 3-MFMA, bias + int16-grid quant epilogue.
__global__ __launch_bounds__(256, 2) void gemm_proj_i8(
    const int8_t* __restrict__ Ahi, const int8_t* __restrict__ Alo,
    const int8_t* __restrict__ Bhi, const int8_t* __restrict__ Blo,
    const float* __restrict__ biasQ, const float* __restrict__ biasK,
    int8_t* __restrict__ Ch, int8_t* __restrict__ Cl)
{
  __shared__ __align__(16) int8_t sAh[128 * 64];
  __shared__ __align__(16) int8_t sAl[128 * 64];
  __shared__ __align__(16) int8_t sBh[128 * 64];
  __shared__ __align__(16) int8_t sBl[128 * 64];

  const int tid  = threadIdx.x;
  const int wave = tid >> 6;
  const int lane = tid & 63;
  const int quad = lane >> 4;
  const int t16  = lane & 15;
  const int wm   = wave & 1;
  const int wn   = wave >> 1;
  const int row0 = blockIdx.y * 128;
  const int col0 = blockIdx.x * 128;

  const int seg  = lane & 3;
  const int rsub = lane >> 2;

  int4v hh[4][4], cc[4][4];
#pragma unroll
  for (int i = 0; i < 4; ++i)
#pragma unroll
    for (int j = 0; j < 4; ++j) {
      hh[i][j] = (int4v){0, 0, 0, 0};
      cc[i][j] = (int4v){0, 0, 0, 0};
    }

  for (int k0 = 0; k0 < 1024; k0 += 64) {
#pragma unroll
    for (int r = 0; r < 2; ++r) {
      const int trow = r * 64 + wave * 16;
      const size_t goffA = (size_t)(row0 + trow + rsub) * 1024 + k0 + seg * 16;
      const size_t goffB = (size_t)(col0 + trow + rsub) * 1024 + k0 + seg * 16;
      GLOAD_LDS16(Ahi + goffA, &sAh[trow * 64]);
      GLOAD_LDS16(Alo + goffA, &sAl[trow * 64]);
      GLOAD_LDS16(Bhi + goffB, &sBh[trow * 64]);
      GLOAD_LDS16(Blo + goffB, &sBl[trow * 64]);
    }
    __syncthreads();

    int4v ah[4], al[4], bh[4], bl[4];
#pragma unroll
    for (int i = 0; i < 4; ++i) {
      const int ar = (wm * 64 + i * 16 + t16) * 64 + quad * 16;
      ah[i] = *(const int4v*)&sAh[ar];
      al[i] = *(const int4v*)&sAl[ar];
    }
#pragma unroll
    for (int j = 0; j < 4; ++j) {
      const int br = (wn * 64 + j * 16 + t16) * 64 + quad * 16;
      bh[j] = *(const int4v*)&sBh[br];
      bl[j] = *(const int4v*)&sBl[br];
    }

#pragma unroll
    for (int i = 0; i < 4; ++i)
#pragma unroll
      for (int j = 0; j < 4; ++j) {
        hh[i][j] = __builtin_amdgcn_mfma_i32_16x16x64_i8(ah[i], bh[j], hh[i][j], 0, 0, 0);
        cc[i][j] = __builtin_amdgcn_mfma_i32_16x16x64_i8(ah[i], bl[j], cc[i][j], 0, 0, 0);
        cc[i][j] = __builtin_amdgcn_mfma_i32_16x16x64_i8(al[i], bh[j], cc[i][j], 0, 0, 0);
      }
    __syncthreads();
  }

#pragma unroll
  for (int i = 0; i < 4; ++i) {
#pragma unroll
    for (int j = 0; j < 4; ++j) {
      const int ccol = col0 + wn * 64 + j * 16 + t16;
      const float* bp = (ccol < 1024) ? biasQ : (biasK - 1024);
#pragma unroll
      for (int r = 0; r < 4; ++r) {
        const int crow = row0 + wm * 64 + i * 16 + quad * 4 + r;
        float v = P_HH * (float)hh[i][j][r] + P_X * (float)cc[i][j][r] + bp[ccol];
        int hi = (int)lrintf(v * INV_S256);
        hi = hi > 127 ? 127 : (hi < -127 ? -127 : hi);
        int lo = (int)lrintf(v * INV_S - 256.0f * (float)hi);
        lo = lo > 127 ? 127 : (lo < -127 ? -127 : lo);
        Ch[(size_t)crow * 2048 + ccol] = (int8_t)hi;
        Cl[(size_t)crow * 2048 + ccol] = (int8_t)lo;
      }
    }
  }
}

// ---------------------------------------------------------------------------
// AV: out = sum_t beta_t (E_t x). 512 threads, two wave-groups (z = wave>>2)
// doing in-block split-K=2 in lockstep; beta computed from stats in the
// prologue into LDS; cross-group add via LDS; direct fp32 store to out.
// XCD swizzle: 8 col-blocks of one 128-row band share (blockIdx % 8).
__global__ __launch_bounds__(512) void gemm_av(
    const uint16_t* __restrict__ E, const uint16_t* __restrict__ B,
    const float2* __restrict__ stats, float* __restrict__ out)
{
  __shared__ __align__(16) uint16_t stage[16384];  // 32 KB: [z][sA | sB]
  __shared__ float betaS[128 * 33];                // padded vs bank conflicts

  const int L      = blockIdx.x;        // 0..255
  const int xcd    = L & 7;
  const int rest   = L >> 3;            // 0..31
  const int colb   = rest & 7;          // 0..7
  const int bandHi = rest >> 3;         // 0..3
  const int band   = xcd + 8 * bandHi;  // 0..31
  const int row0   = band * 128;
  const int col0   = colb * 128;

  const int tid  = threadIdx.x;
  const int wave = tid >> 6;
  const int z    = wave >> 2;           // wave-group = K-half
  const int gw   = wave & 3;            // group-local wave
  const int lane = tid & 63;
  const int quad = lane >> 4;
  const int t16  = lane & 15;
  const int wm   = gw & 1;
  const int wn   = gw >> 1;
  const int seg  = lane & 3;
  const int rsub = lane >> 2;

  // ---- beta prologue: threads 0..127, one row each ------------------------
  if (tid < 128) {
    const int row = row0 + tid;
    float2 st[32];
    float m = -3.0e38f;
#pragma unroll
    for (int t = 0; t < 32; ++t) {
      st[t] = stats[(size_t)row * 32 + t];
      m = fmaxf(m, st[t].x);
    }
    float l = 0.f;
#pragma unroll
    for (int t = 0; t < 32; ++t) l += st[t].y * __expf(st[t].x - m);
    const float inv = 1.0f / l;
#pragma unroll
    for (int t = 0; t < 32; ++t)
      betaS[tid * 33 + t] = __expf(st[t].x - m) * inv;
  }
  __syncthreads();

  uint16_t* sA = &stage[z * 8192];
  uint16_t* sB = &stage[z * 8192 + 4096];

  float4v acc[4][4];
#pragma unroll
  for (int i = 0; i < 4; ++i)
#pragma unroll
    for (int j = 0; j < 4; ++j)
      acc[i][j] = (float4v){0.f, 0.f, 0.f, 0.f};

  // ---- K loop: group z covers t = z*16 .. z*16+15 (lockstep barriers) -----
  for (int tt = 0; tt < 16; ++tt) {
    const int t = z * 16 + tt;
    _Float16 bb[4];
#pragma unroll
    for (int i = 0; i < 4; ++i)
      bb[i] = (_Float16)betaS[(wm * 64 + i * 16 + t16) * 33 + t];

#pragma unroll
    for (int kk = 0; kk < 4; ++kk) {
      const int k0 = t * 128 + kk * 32;
#pragma unroll
      for (int r = 0; r < 2; ++r) {
        const int trow = r * 64 + gw * 16;
        const size_t goffA = (size_t)(row0 + trow + rsub) * 4096 + k0 + seg * 8;
        const size_t goffB = (size_t)(col0 + trow + rsub) * 4096 + k0 + seg * 8;
        GLOAD_LDS16(E + goffA, &sA[trow * 32]);
        GLOAD_LDS16(B + goffB, &sB[trow * 32]);
      }
      __syncthreads();

      half8 af[4], bf[4];
#pragma unroll
      for (int i = 0; i < 4; ++i) {
        af[i] = *(const half8*)&sA[(wm * 64 + i * 16 + t16) * 32 + quad * 8];
        half8 bs;
#pragma unroll
        for (int c = 0; c < 8; ++c) bs[c] = bb[i];
        af[i] = af[i] * bs;
      }
#pragma unroll
      for (int j = 0; j < 4; ++j)
        bf[j] = *(const half8*)&sB[(wn * 64 + j * 16 + t16) * 32 + quad * 8];

#pragma unroll
      for (int i = 0; i < 4; ++i)
#pragma unroll
        for (int j = 0; j < 4; ++j)
          acc[i][j] = __builtin_amdgcn_mfma_f32_16x16x32_f16(af[i], bf[j], acc[i][j], 0, 0, 0);
      __syncthreads();
    }
  }

  // ---- combine group1 -> group0 via LDS (two 32 KB halves) ----------------
  float* xfer = (float*)stage;  // 8192 floats
#pragma unroll
  for (int h = 0; h < 2; ++h) {
    if (z == 1) {
#pragma unroll
      for (int i = 2 * h; i < 2 * h + 2; ++i)
#pragma unroll
        for (int j = 0; j < 4; ++j)
#pragma unroll
          for (int r = 0; r < 4; ++r) {
            const int e = (i - 2 * h) * 16 + j * 4 + r;
            xfer[e * 256 + gw * 64 + lane] = acc[i][j][r];
          }
    }
    __syncthreads();
    if (z == 0) {
#pragma unroll
      for (int i = 2 * h; i < 2 * h + 2; ++i)
#pragma unroll
        for (int j = 0; j < 4; ++j)
#pragma unroll
          for (int r = 0; r < 4; ++r) {
            const int e = (i - 2 * h) * 16 + j * 4 + r;
            acc[i][j][r] += xfer[e * 256 + gw * 64 + lane];
          }
    }
    __syncthreads();
  }

  // ---- store (group0 only) ------------------------------------------------
  if (z == 0) {
#pragma unroll
    for (int i = 0; i < 4; ++i) {
#pragma unroll
      for (int j = 0; j < 4; ++j) {
        const int ccol = col0 + wn * 64 + j * 16 + t16;
#pragma unroll
        for (int r = 0; r < 4; ++r) {
          const int crow = row0 + wm * 64 + i * 16 + quad * 4 + r;
          out[(size_t)crow * 1024 + ccol] = acc[i][j][r];
        }
      }
    }
  }
}

// ---------------------------------------------------------------------------
// Fused quant + transpose-cast.
// Blocks 0..6143: quantize x (+-6 grid) / Wq / Wk (+-0.25 grid) to i8 planes.
// Blocks 6144..10239: transpose-cast x -> xT fp16 (32x32 tiles, 256 thr).
__global__ __launch_bounds__(256) void quantT(
    const float* __restrict__ x, const float* __restrict__ Wq,
    const float* __restrict__ Wk,
    int8_t* __restrict__ xhi, int8_t* __restrict__ xlo,
    int8_t* __restrict__ whi, int8_t* __restrict__ wlo,
    uint16_t* __restrict__ xT)
{
  if (blockIdx.x < 6144) {
    int i = blockIdx.x * 256 + threadIdx.x;  // 0..1572863
    const float* src; int8_t* dh; int8_t* dl; int idx; float s256, s;
    if (i < 1048576)      { src = x;  idx = i;           dh = xhi; dl = xlo;
                            s256 = INV_S256; s = INV_S; }
    else if (i < 1310720) { src = Wq; idx = i - 1048576; dh = whi; dl = wlo;
                            s256 = 512.0f; s = 131072.0f; }
    else                  { src = Wk; idx = i - 1310720; dh = whi + 1048576;
                            dl = wlo + 1048576; s256 = 512.0f; s = 131072.0f; }
    float4 v = ((const float4*)src)[idx];
    float vv[4] = {v.x, v.y, v.z, v.w};
    int hp = 0, lp = 0;
#pragma unroll
    for (int c = 0; c < 4; ++c) {
      int h = (int)lrintf(vv[c] * s256);
      h = h > 127 ? 127 : (h < -127 ? -127 : h);
      int l = (int)lrintf(vv[c] * s - 256.0f * (float)h);
      l = l > 127 ? 127 : (l < -127 ? -127 : l);
      hp |= (h & 0xff) << (8 * c);
      lp |= (l & 0xff) << (8 * c);
    }
    ((int*)dh)[idx] = hp;
    ((int*)dl)[idx] = lp;
  } else {
    __shared__ float tile[32][33];
    const int tb = blockIdx.x - 6144;   // 0..4095
    const int bx = tb & 31;             // D/32
    const int by = tb >> 5;             // N/32
    const int tx = threadIdx.x & 31;
    const int ty = threadIdx.x >> 5;    // 0..7
#pragma unroll
    for (int p = 0; p < 4; ++p) {
      const int row = by * 32 + ty + p * 8;
      tile[ty + p * 8][tx] = x[(size_t)row * 1024 + bx * 32 + tx];
    }
    __syncthreads();
#pragma unroll
    for (int p = 0; p < 4; ++p) {
      const int oc = ty + p * 8;  // local col in x == local row in xT
      __half hv = __float2half_rn(tile[tx][oc]);
      xT[(size_t)(bx * 32 + oc) * 4096 + by * 32 + tx] = *(uint16_t*)&hv;
    }
  }
}

extern "C" void kernel_launch(void* const* d_in, const int* in_sizes, int n_in,
                              void* d_out, int out_size, void* d_ws, size_t ws_size,
                              hipStream_t stream) {
  const int N = 4096, D = 1024;
  const float* x  = (const float*)d_in[0];
  const float* Wq = (const float*)d_in[1];
  const float* bq = (const float*)d_in[2];
  const float* Wk = (const float*)d_in[3];
  const float* bk = (const float*)d_in[4];
  float* out = (float*)d_out;

  // workspace layout (MiB offsets)
  char* w = (char*)d_ws;
  const size_t MiB = 1024 * 1024;
  int8_t*    xq_hi  = (int8_t*)   (w + 0  * MiB);  // [N x D]
  int8_t*    xq_lo  = (int8_t*)   (w + 4  * MiB);
  int8_t*    Wqk_hi = (int8_t*)   (w + 8  * MiB);  // [2048 x D]
  int8_t*    Wqk_lo = (int8_t*)   (w + 10 * MiB);
  int8_t*    qk_hi  = (int8_t*)   (w + 12 * MiB);  // [N x 2048]
  int8_t*    qk_lo  = (int8_t*)   (w + 20 * MiB);
  _Float16*  E      = (_Float16*) (w + 36 * MiB);  // [N x N] fp16, 32 MiB
  float2*    stats  = (float2*)   (w + 68 * MiB);  // [N x 32] (m,l), 1 MiB
  uint16_t*  xTh    = (uint16_t*) (w + 72 * MiB);  // [D x N] fp16
  // total 80 MiB

  // 1) fused quantization + transpose-cast  (6144 + 4096 blocks)
  quantT<<<10240, 256, 0, stream>>>(x, Wq, Wk, xq_hi, xq_lo, Wqk_hi, Wqk_lo,
                                    xTh);

  // 2) fused qk projection: i8 16x16x64, 3-MFMA, bias+quant epilogue
  gemm_proj_i8<<<dim3(2048 / 128, N / 128), 256, 0, stream>>>(
      xq_hi, xq_lo, Wqk_hi, Wqk_lo, bq, bk, qk_hi, qk_lo);

  // 3) S = q k^T + tile softmax stats -> E fp16, stats (m_t, l_t)
  gemm_s_stats<<<dim3(N / 128, N / 128), 256, 0, stream>>>(
      qk_hi, qk_lo, qk_hi + 1024, qk_lo + 1024, E, stats);

  // 4) out = sum_t beta_t (E_t x): beta prologue + in-block split-K=2
  gemm_av<<<256, 512, 0, stream>>>((const uint16_t*)E, xTh, stats, out);

  (void)in_sizes; (void)n_in; (void)out_size; (void)ws_size;
}